// Round 11
// baseline (728.204 us; speedup 1.0000x reference)
//
#include <hip/hip_runtime.h>
#include <cmath>

// VanillaRNN: B=256, T=128, D=1, H=2048, C=10
// R22: R19 (552 us persist, verified) + barrier-B removal on the rotation
// path via per-wave aggregated signaling.
// R20/R21 post-mortem: rocprofv3 replays dispatches WITHOUT the stream's
// hipMemsetAsync ops. R14-R19 are benign under dirty-workspace replay
// (flags>=threshold => polls pass instantly); the XCD roll-call was not
// (stale decision word + re-registration => disagreeing mappings => a
// (g,C) flag never signaled => unbounded poll => GPU hang). Rule adopted:
// all protocol state must be BENIGN under replay-without-memset. XCD-local
// scope is parked (no run-invariant consensus input available).
// R22 delta vs R19 (ROT=1 path only):
//   - publish slot t, then PER-WAVE s_waitcnt(0) drain (R17-validated
//     construct) and lane0 fetch_add(+1) on the block's SINGLE per-t flag
//     line (not R17's 8 separate lines, which flooded the MALL);
//     consumers poll v >= 8 (8 waves). Barrier B deleted.
//   - red[] double-buffered red[t&1] (R17-validated): with B gone, wave
//     skew is bounded by barrier A at <=1 iteration; dbuf covers it.
//   - rotation already removed the h-overwrite hazard that B's block-wide
//     ordering proof served; per-t flag lines are distinct addresses.
// Replay-safe: stale flag values >= 8 => instant poll pass, clean exit.
// ROT=0 fallback (ws too small) keeps the exact R18 protocol (barrier B +
// tid0 single +1, poll v>=1, atomic frag loads, ping-pong buffers).

#define B_ 256
#define T_ 128
#define H_ 2048
#define C_ 10

typedef _Float16 half_t;
typedef _Float16 half8 __attribute__((ext_vector_type(8)));
typedef _Float16 half4v __attribute__((ext_vector_type(4)));
typedef float floatx4 __attribute__((ext_vector_type(4)));
typedef unsigned long long u64;
typedef unsigned long long u64x2 __attribute__((ext_vector_type(2)));

#define BUF_U64 131072        // one h buffer: 256*2048 halfs = 1 MB
#define NSLOT 127             // published slots 0..126

// flag array: dword index  t*(8*32*32) + (g*32 + C)*32  (one 128B line per
// flag). t in [0,127), g in [0,8), C = producer block-in-group [0,32).
#define FLAG_DWORDS (128 * 8 * 32 * 32)   // 4 MB

__device__ __forceinline__ float fast_tanh(float v) {
    return 1.0f - 2.0f / (__expf(2.0f * v) + 1.0f);
}

// publish one u64 of packed halfs via RMW (commits+allocates at MALL; the
// returned old value is kept live so the swap cannot be demoted to a
// posted store)
__device__ __forceinline__ void publish_u64(u64* p, u64 v) {
    u64 old = __hip_atomic_exchange(p, v, __ATOMIC_RELAXED,
                                    __HIP_MEMORY_SCOPE_AGENT);
    asm volatile("" :: "v"(old));
}

// wave-level drain: all of this wave's outstanding VMEM (incl. its 64
// lanes' exchange RMWs) committed at the coherence point before anything
// after this line issues.  [R17-validated construct]
__device__ __forceinline__ void wave_drain() {
    __builtin_amdgcn_sched_barrier(0);
    __builtin_amdgcn_s_waitcnt(0);        // vmcnt(0) lgkmcnt(0) expcnt(0)
    __builtin_amdgcn_sched_barrier(0);
}

// slab base (u64 units) of published slot s
template <int ROT>
__device__ __forceinline__ size_t slot_base(int s) {
    return ROT ? (size_t)s * BUF_U64
               : (size_t)((s + 1) & 1) * BUF_U64;   // legacy ping-pong
}

// ---- persistent RNN kernel: 256 blocks x 512 thr (8 waves, 2/SIMD) ----
template <int ROT>
__global__ void __launch_bounds__(512, 2) rnn_persist(
    const float* __restrict__ x,   // [B_,T_]
    const float* __restrict__ U,   // [H_]
    const float* __restrict__ W,   // [H_,H_] fp32
    const float* __restrict__ bh,  // [H_]
    const float* __restrict__ V,   // [C_,H_]
    const float* __restrict__ bp,  // [C_]
    half_t* __restrict__ hbase,    // ROT: 127 x 1 MB slots; else 2 x 1 MB
    float* __restrict__ hf32,      // d_out h_last region (row-major fp32)
    float* __restrict__ outp,      // d_out projection region [B_,C_] (zeroed)
    unsigned* __restrict__ flags)
{
    const int tid  = threadIdx.x;
    const int wave = tid >> 6, lane = tid & 63;
    const int quad = lane >> 4, lq = lane & 15;
    const int id   = blockIdx.x;
    const int g    = id & 7;                      // group (~XCD under id%8)
    const int C    = id >> 3;                     // block-in-group 0..31
    const int m0   = g * 32;                      // group rows m0..m0+31
    const int n0   = C * 64;                      // block cols n0..n0+63

    // ---- one-time: W frags for this wave's K-range -> regs (fp16) ----
    half8 Bw[8][4];
#pragma unroll
    for (int kk = 0; kk < 8; ++kk) {
#pragma unroll
        for (int nt = 0; nt < 4; ++nt) {
            const int gn = n0 + nt * 16 + lq;
            const int k0 = wave * 256 + kk * 32 + quad * 8;
            const float4 w0 = *(const float4*)&W[(size_t)gn * H_ + k0];
            const float4 w1 = *(const float4*)&W[(size_t)gn * H_ + k0 + 4];
            const float wv[8] = {w0.x, w0.y, w0.z, w0.w, w1.x, w1.y, w1.z, w1.w};
            half8 hw;
#pragma unroll
            for (int j = 0; j < 8; ++j) hw[j] = (half_t)wv[j];
            Bw[kk][nt] = hw;
        }
    }

    // epilogue-owner role: wave w owns output tile (mtO, ntO); 2x4 = 8 tiles
    const int mtO = wave & 1, ntO = wave >> 1;
    const float uvO = U[n0 + ntO * 16 + lq];
    const float bvO = bh[n0 + ntO * 16 + lq];

    __shared__ floatx4 red[2][2][8][4][64];       // DOUBLE-buffered, 128 KB
    __shared__ __align__(16) float Tr[8][16][20]; // per-wave transpose, 10 KB
    __shared__ float xs[T_][32];                  // x slab transposed, 16 KB

    for (int i = tid; i < 32 * T_; i += 512) {    // one-time x staging
        const int r = i & 31, tt = i >> 5;
        xs[tt][r] = x[(size_t)(m0 + r) * T_ + tt];
    }
    __syncthreads();

    // step-0 producer mapping (validated): u64 index == tid
    const int prow = (tid >> 8) * 16 + ((tid >> 1) & 15);   // local row 0..31
    const int pcol = ((tid >> 7) & 1) * 32 + ((tid >> 5) & 3) * 8 + (tid & 1) * 4;
    const size_t slab = (size_t)g * 16384;                  // u64 units (128 KB)
    const size_t pdst = slab + (size_t)C * 512 + tid;       // within-buffer
    const size_t cbase = slab + (size_t)wave * 2048 + (size_t)lane * 2;

    // owner-publish slot (validated sigma): row mtO*16+lq,
    // cols ntO*16 + quad*4 .. +3
    const int sigma = mtO * 256 + (ntO >> 1) * 128
                    + ((ntO & 1) * 2 + (quad >> 1)) * 32 + lq * 2 + (quad & 1);
    const size_t pdst_o = slab + (size_t)C * 512 + sigma;

    // flag addresses (one per-t 128B line per block)
    unsigned* myflag_base = flags + ((size_t)g * 32 + C) * 32;   // + t*8192
    const unsigned* pollp = flags + ((size_t)g * 32 + wave * 4 + (lane & 3)) * 32;

    // poll threshold: ROT=1 -> 8 per-wave increments; ROT=0 -> tid0's 1
    const unsigned TH = ROT ? 8u : 1u;

    // ---- step 0: h1 = tanh(x*U + bh) -> slot 0, signal ----
    {
        const float xb = xs[0][prow];
        half4v hv;
#pragma unroll
        for (int j = 0; j < 4; ++j) {
            const int n = n0 + pcol + j;
            hv[j] = (half_t)fast_tanh(xb * U[n] + bh[n]);
        }
        publish_u64((u64*)hbase + slot_base<ROT>(0) + pdst,
                    __builtin_bit_cast(u64, hv));
    }
    if (ROT) {
        wave_drain();             // this wave's 64 publishes committed
        if (lane == 0)
            __hip_atomic_fetch_add(myflag_base, 1u, __ATOMIC_RELAXED,
                                   __HIP_MEMORY_SCOPE_AGENT);
    } else {
        __syncthreads();
        if (tid == 0)
            __hip_atomic_fetch_add(myflag_base, 1u, __ATOMIC_RELAXED,
                                   __HIP_MEMORY_SCOPE_AGENT);
    }

    // ---- steps t = 1..127 : consume slot t-1, publish slot t ----
    for (int t = 1; t < T_; ++t) {
        const u64* pw = (const u64*)hbase + slot_base<ROT>(t - 1) + cbase;
        u64* pout     = (u64*)hbase + slot_base<ROT>(t);

        // wave-level poll: my 4 producers for slot t-1 (v >= TH)
        {
            const unsigned* fp = pollp + (size_t)(t - 1) * (8 * 32 * 32);
            while (true) {
                const unsigned v = __hip_atomic_load(fp, __ATOMIC_RELAXED,
                                                     __HIP_MEMORY_SCOPE_AGENT);
                if (__all(v >= TH)) break;
                __builtin_amdgcn_s_sleep(1);
            }
            asm volatile("" ::: "memory");        // no load hoisting above poll
        }

        floatx4 acc[2][4] = {};

        u64 rl[8], rh[8];                         // ring-8 of 16B frags
        auto issue = [&](int f) {
            // f -> (c'=f>>2, mt=(f>>1)&1, kc=f&1)
            const u64* q = pw + (size_t)((f >> 2) * 512 + ((f >> 1) & 1) * 256
                                         + (f & 1) * 128);
            if (ROT) {
                const u64x2 v = *(const u64x2*)q; // plain cached dwordx4
                rl[f & 7] = v.x;
                rh[f & 7] = v.y;
            } else {
                rl[f & 7] = __hip_atomic_load(q, __ATOMIC_RELAXED,
                                              __HIP_MEMORY_SCOPE_AGENT);
                rh[f & 7] = __hip_atomic_load(q + 1, __ATOMIC_RELAXED,
                                              __HIP_MEMORY_SCOPE_AGENT);
            }
        };
#pragma unroll
        for (int f = 0; f < 8; ++f) issue(f);
#pragma unroll
        for (int f = 0; f < 16; ++f) {            // 16 A-frags
            const int cp = f >> 2, mt = (f >> 1) & 1, kc = f & 1;
            const int kk = cp * 2 + kc;
            u64x2 bits; bits.x = rl[f & 7]; bits.y = rh[f & 7];
            const half8 av = __builtin_bit_cast(half8, bits);
            if (f + 8 < 16) issue(f + 8);
            acc[mt][0] = __builtin_amdgcn_mfma_f32_16x16x32_f16(av, Bw[kk][0], acc[mt][0], 0, 0, 0);
            acc[mt][1] = __builtin_amdgcn_mfma_f32_16x16x32_f16(av, Bw[kk][1], acc[mt][1], 0, 0, 0);
            acc[mt][2] = __builtin_amdgcn_mfma_f32_16x16x32_f16(av, Bw[kk][2], acc[mt][2], 0, 0, 0);
            acc[mt][3] = __builtin_amdgcn_mfma_f32_16x16x32_f16(av, Bw[kk][3], acc[mt][3], 0, 0, 0);
        }

        // ---- 8-way K-split reduction (double-buffered) ----
#pragma unroll
        for (int mt = 0; mt < 2; ++mt)
#pragma unroll
            for (int nt = 0; nt < 4; ++nt)
                red[t & 1][mt][wave][nt][lane] = acc[mt][nt];
        __syncthreads();                          // barrier A (red ready)

        // ---- per-wave owner epilogue: sum, tanh, transpose, publish ----
        {
            float xr[4];
#pragma unroll
            for (int r = 0; r < 4; ++r) xr[r] = xs[t][mtO * 16 + quad * 4 + r];
            floatx4 s = red[t & 1][mtO][0][ntO][lane];
#pragma unroll
            for (int ww = 1; ww < 8; ++ww) s += red[t & 1][mtO][ww][ntO][lane];
#pragma unroll
            for (int r = 0; r < 4; ++r) {
                const float pre = s[r] + xr[r] * uvO + bvO;
                Tr[wave][quad * 4 + r][lq] = fast_tanh(pre);   // wave-private
            }
            // DS pipe is in-order within a wave: read back transposed
            const float4 fr = *(const float4*)&Tr[wave][lq][quad * 4];

            if (t < T_ - 1) {
                half4v hv;
                hv[0] = (half_t)fr.x; hv[1] = (half_t)fr.y;
                hv[2] = (half_t)fr.z; hv[3] = (half_t)fr.w;
                publish_u64(pout + pdst_o, __builtin_bit_cast(u64, hv));
                if (ROT) {
                    wave_drain();     // this wave's publishes committed
                    if (lane == 0)    // aggregate on the SINGLE per-t line
                        __hip_atomic_fetch_add(
                            myflag_base + (size_t)t * (8 * 32 * 32), 1u,
                            __ATOMIC_RELAXED, __HIP_MEMORY_SCOPE_AGENT);
                } else {
                    __syncthreads();  // barrier B (legacy path only)
                    if (tid == 0)
                        __hip_atomic_fetch_add(
                            myflag_base + (size_t)t * (8 * 32 * 32), 1u,
                            __ATOMIC_RELAXED, __HIP_MEMORY_SCOPE_AGENT);
                }
            } else {
                // final h_128 -> d_out fp32
                float* fd = hf32 + (size_t)(m0 + mtO * 16 + lq) * H_
                          + n0 + ntO * 16 + quad * 4;
                *(float4*)fd = make_float4(fr.x, fr.y, fr.z, fr.w);
                __syncthreads();      // all waves' Tr tiles complete
                // fused projection: partial out[32,10] = Tr-tiles @ V^T
                if (tid < 32 * C_) {
                    const int r = tid & 31, c = tid >> 5;    // c in [0,10)
                    float sacc = (C == 0) ? bp[c] : 0.0f;
                    const float* vr = V + (size_t)c * H_ + n0;
#pragma unroll 8
                    for (int n = 0; n < 64; ++n)
                        sacc += Tr[(n >> 4) * 2 + (r >> 4)][r & 15][n & 15] * vr[n];
                    atomicAdd(&outp[(size_t)(m0 + r) * C_ + c], sacc);
                }
            }
        }
    }
}

extern "C" void kernel_launch(void* const* d_in, const int* in_sizes, int n_in,
                              void* d_out, int out_size, void* d_ws, size_t ws_size,
                              hipStream_t stream) {
    const float* x  = (const float*)d_in[0];
    const float* U  = (const float*)d_in[1];
    const float* W  = (const float*)d_in[2];
    const float* V  = (const float*)d_in[3];
    const float* bh = (const float*)d_in[4];
    const float* bp = (const float*)d_in[5];

    float* out_h = (float*)d_out;                 // [B_*H_] fp32 h_last
    float* outp  = out_h + (size_t)B_ * H_;       // [B_*C_]

    unsigned* flags = (unsigned*)d_ws;                              // 4 MB
    half_t* hbase   = (half_t*)((char*)d_ws + (size_t)4 * 1024 * 1024);

    // rotation needs 4 MB flags + 127 x 1 MB slots = 131 MB
    const size_t need = (size_t)(4 + NSLOT) * 1024 * 1024;
    const int rot = ws_size >= need;

    hipMemsetAsync(flags, 0, FLAG_DWORDS * sizeof(unsigned), stream);
    hipMemsetAsync(outp, 0, (size_t)B_ * C_ * sizeof(float), stream);

    if (rot)
        rnn_persist<1><<<dim3(256), dim3(512), 0, stream>>>(
            x, U, W, bh, V, bp, hbase, out_h, outp, flags);
    else
        rnn_persist<0><<<dim3(256), dim3(512), 0, stream>>>(
            x, U, W, bh, V, bp, hbase, out_h, outp, flags);
}

// Round 12
// 595.706 us; speedup vs baseline: 1.2224x; 1.2224x over previous
//
#include <hip/hip_runtime.h>
#include <cmath>

// VanillaRNN: B=256, T=128, D=1, H=2048, C=10
// R23: R19 protocol + barrier-B removal done RIGHT (LDS last-wave-out).
// R22 post-mortem: 8 per-wave RMWs on the SAME flag line serialize at the
// MALL; consumers need v>=8 = the LAST of that chain => flag-ready LATER
// than R19's barrier-B + single tid0 RMW (552 -> 680 regression). Fix:
// aggregate the "all 8 waves drained" event in LDS (one atomicAdd, ~30cy),
// and have ONLY the 8th wave issue the single global flag RMW:
//   publish (agent atomic-exchange, commits at MALL)
//   -> per-wave s_waitcnt(0) drain (pinned by sched_barrier)
//   -> LDS atomicAdd(&lcnt, 1)
//   -> (old==7) ? { lcnt = 0; global fetch_add(flag_t, 1) } : fall through
// Consumers poll v >= 1 (unchanged from R19). Ordering proof: wave's LDS
// inc is program-ordered after its drain; old==7 => all 8 waves' publishes
// committed; the flag RMW is dependent on the LDS return value. Reset is
// safe: it precedes the 8th wave's barrier-A(t+1) arrival, and every other
// wave's next inc follows barrier-A(t+1) release. Early waves skip any
// barrier and poll immediately (overlap with last wave's drain).
// red[] double-buffered red[t&1] (R17/R22-validated) covers the <=1-step
// wave skew barrier B used to prevent. Rotation, sigma owner-publish, Tr
// transpose, fused projection: byte-identical to R19/R22. Replay-safe:
// stale flags >= 1 => polls pass instantly (R20/R21 hang rule).
// ROT=0 fallback = exact R18 (barrier B + tid0, ping-pong, atomic loads).

#define B_ 256
#define T_ 128
#define H_ 2048
#define C_ 10

typedef _Float16 half_t;
typedef _Float16 half8 __attribute__((ext_vector_type(8)));
typedef _Float16 half4v __attribute__((ext_vector_type(4)));
typedef float floatx4 __attribute__((ext_vector_type(4)));
typedef unsigned long long u64;
typedef unsigned long long u64x2 __attribute__((ext_vector_type(2)));

#define BUF_U64 131072        // one h buffer: 256*2048 halfs = 1 MB
#define NSLOT 127             // published slots 0..126

// flag array: dword index  t*(8*32*32) + (g*32 + C)*32  (one 128B line per
// flag). t in [0,127), g in [0,8), C = producer block-in-group [0,32).
#define FLAG_DWORDS (128 * 8 * 32 * 32)   // 4 MB

__device__ __forceinline__ float fast_tanh(float v) {
    return 1.0f - 2.0f / (__expf(2.0f * v) + 1.0f);
}

// publish one u64 of packed halfs via RMW (commits+allocates at MALL; the
// returned old value is kept live so the swap cannot be demoted to a
// posted store)
__device__ __forceinline__ void publish_u64(u64* p, u64 v) {
    u64 old = __hip_atomic_exchange(p, v, __ATOMIC_RELAXED,
                                    __HIP_MEMORY_SCOPE_AGENT);
    asm volatile("" :: "v"(old));
}

// wave-level drain: all of this wave's outstanding VMEM (incl. its 64
// lanes' exchange RMWs) committed at the coherence point before anything
// after this line issues.  [R17-validated construct]
__device__ __forceinline__ void wave_drain() {
    __builtin_amdgcn_sched_barrier(0);
    __builtin_amdgcn_s_waitcnt(0);        // vmcnt(0) lgkmcnt(0) expcnt(0)
    __builtin_amdgcn_sched_barrier(0);
}

// slab base (u64 units) of published slot s
template <int ROT>
__device__ __forceinline__ size_t slot_base(int s) {
    return ROT ? (size_t)s * BUF_U64
               : (size_t)((s + 1) & 1) * BUF_U64;   // legacy ping-pong
}

// ---- persistent RNN kernel: 256 blocks x 512 thr (8 waves, 2/SIMD) ----
template <int ROT>
__global__ void __launch_bounds__(512, 2) rnn_persist(
    const float* __restrict__ x,   // [B_,T_]
    const float* __restrict__ U,   // [H_]
    const float* __restrict__ W,   // [H_,H_] fp32
    const float* __restrict__ bh,  // [H_]
    const float* __restrict__ V,   // [C_,H_]
    const float* __restrict__ bp,  // [C_]
    half_t* __restrict__ hbase,    // ROT: 127 x 1 MB slots; else 2 x 1 MB
    float* __restrict__ hf32,      // d_out h_last region (row-major fp32)
    float* __restrict__ outp,      // d_out projection region [B_,C_] (zeroed)
    unsigned* __restrict__ flags)
{
    const int tid  = threadIdx.x;
    const int wave = tid >> 6, lane = tid & 63;
    const int quad = lane >> 4, lq = lane & 15;
    const int id   = blockIdx.x;
    const int g    = id & 7;                      // group (~XCD under id%8)
    const int C    = id >> 3;                     // block-in-group 0..31
    const int m0   = g * 32;                      // group rows m0..m0+31
    const int n0   = C * 64;                      // block cols n0..n0+63

    // ---- one-time: W frags for this wave's K-range -> regs (fp16) ----
    half8 Bw[8][4];
#pragma unroll
    for (int kk = 0; kk < 8; ++kk) {
#pragma unroll
        for (int nt = 0; nt < 4; ++nt) {
            const int gn = n0 + nt * 16 + lq;
            const int k0 = wave * 256 + kk * 32 + quad * 8;
            const float4 w0 = *(const float4*)&W[(size_t)gn * H_ + k0];
            const float4 w1 = *(const float4*)&W[(size_t)gn * H_ + k0 + 4];
            const float wv[8] = {w0.x, w0.y, w0.z, w0.w, w1.x, w1.y, w1.z, w1.w};
            half8 hw;
#pragma unroll
            for (int j = 0; j < 8; ++j) hw[j] = (half_t)wv[j];
            Bw[kk][nt] = hw;
        }
    }

    // epilogue-owner role: wave w owns output tile (mtO, ntO); 2x4 = 8 tiles
    const int mtO = wave & 1, ntO = wave >> 1;
    const float uvO = U[n0 + ntO * 16 + lq];
    const float bvO = bh[n0 + ntO * 16 + lq];

    __shared__ floatx4 red[2][2][8][4][64];       // DOUBLE-buffered, 128 KB
    __shared__ __align__(16) float Tr[8][16][20]; // per-wave transpose, 10 KB
    __shared__ float xs[T_][32];                  // x slab transposed, 16 KB
    __shared__ unsigned lcnt;                     // last-wave-out counter

    for (int i = tid; i < 32 * T_; i += 512) {    // one-time x staging
        const int r = i & 31, tt = i >> 5;
        xs[tt][r] = x[(size_t)(m0 + r) * T_ + tt];
    }
    if (tid == 0) lcnt = 0u;
    __syncthreads();

    // step-0 producer mapping (validated): u64 index == tid
    const int prow = (tid >> 8) * 16 + ((tid >> 1) & 15);   // local row 0..31
    const int pcol = ((tid >> 7) & 1) * 32 + ((tid >> 5) & 3) * 8 + (tid & 1) * 4;
    const size_t slab = (size_t)g * 16384;                  // u64 units (128 KB)
    const size_t pdst = slab + (size_t)C * 512 + tid;       // within-buffer
    const size_t cbase = slab + (size_t)wave * 2048 + (size_t)lane * 2;

    // owner-publish slot (validated sigma): row mtO*16+lq,
    // cols ntO*16 + quad*4 .. +3
    const int sigma = mtO * 256 + (ntO >> 1) * 128
                    + ((ntO & 1) * 2 + (quad >> 1)) * 32 + lq * 2 + (quad & 1);
    const size_t pdst_o = slab + (size_t)C * 512 + sigma;

    // flag addresses (one per-t 128B line per block)
    unsigned* myflag_base = flags + ((size_t)g * 32 + C) * 32;   // + t*8192
    const unsigned* pollp = flags + ((size_t)g * 32 + wave * 4 + (lane & 3)) * 32;

    // last-wave-out signal: drain this wave, inc LDS counter; 8th wave
    // resets the counter and issues the single global flag RMW.
    auto wave_signal = [&](unsigned* fl) {
        wave_drain();
        if (lane == 0) {
            const unsigned prev = atomicAdd(&lcnt, 1u);
            if (prev == 7u) {
                lcnt = 0u;                        // reset for next step
                __hip_atomic_fetch_add(fl, 1u, __ATOMIC_RELAXED,
                                       __HIP_MEMORY_SCOPE_AGENT);
            }
        }
    };

    // ---- step 0: h1 = tanh(x*U + bh) -> slot 0, signal ----
    {
        const float xb = xs[0][prow];
        half4v hv;
#pragma unroll
        for (int j = 0; j < 4; ++j) {
            const int n = n0 + pcol + j;
            hv[j] = (half_t)fast_tanh(xb * U[n] + bh[n]);
        }
        publish_u64((u64*)hbase + slot_base<ROT>(0) + pdst,
                    __builtin_bit_cast(u64, hv));
    }
    if (ROT) {
        wave_signal(myflag_base);
    } else {
        __syncthreads();
        if (tid == 0)
            __hip_atomic_fetch_add(myflag_base, 1u, __ATOMIC_RELAXED,
                                   __HIP_MEMORY_SCOPE_AGENT);
    }

    // ---- steps t = 1..127 : consume slot t-1, publish slot t ----
    for (int t = 1; t < T_; ++t) {
        const u64* pw = (const u64*)hbase + slot_base<ROT>(t - 1) + cbase;
        u64* pout     = (u64*)hbase + slot_base<ROT>(t);

        // wave-level poll: my 4 producers for slot t-1 (v >= 1)
        {
            const unsigned* fp = pollp + (size_t)(t - 1) * (8 * 32 * 32);
            while (true) {
                const unsigned v = __hip_atomic_load(fp, __ATOMIC_RELAXED,
                                                     __HIP_MEMORY_SCOPE_AGENT);
                if (__all(v >= 1u)) break;
                __builtin_amdgcn_s_sleep(1);
            }
            asm volatile("" ::: "memory");        // no load hoisting above poll
        }

        floatx4 acc[2][4] = {};

        u64 rl[8], rh[8];                         // ring-8 of 16B frags
        auto issue = [&](int f) {
            // f -> (c'=f>>2, mt=(f>>1)&1, kc=f&1)
            const u64* q = pw + (size_t)((f >> 2) * 512 + ((f >> 1) & 1) * 256
                                         + (f & 1) * 128);
            if (ROT) {
                const u64x2 v = *(const u64x2*)q; // plain cached dwordx4
                rl[f & 7] = v.x;
                rh[f & 7] = v.y;
            } else {
                rl[f & 7] = __hip_atomic_load(q, __ATOMIC_RELAXED,
                                              __HIP_MEMORY_SCOPE_AGENT);
                rh[f & 7] = __hip_atomic_load(q + 1, __ATOMIC_RELAXED,
                                              __HIP_MEMORY_SCOPE_AGENT);
            }
        };
#pragma unroll
        for (int f = 0; f < 8; ++f) issue(f);
#pragma unroll
        for (int f = 0; f < 16; ++f) {            // 16 A-frags
            const int cp = f >> 2, mt = (f >> 1) & 1, kc = f & 1;
            const int kk = cp * 2 + kc;
            u64x2 bits; bits.x = rl[f & 7]; bits.y = rh[f & 7];
            const half8 av = __builtin_bit_cast(half8, bits);
            if (f + 8 < 16) issue(f + 8);
            acc[mt][0] = __builtin_amdgcn_mfma_f32_16x16x32_f16(av, Bw[kk][0], acc[mt][0], 0, 0, 0);
            acc[mt][1] = __builtin_amdgcn_mfma_f32_16x16x32_f16(av, Bw[kk][1], acc[mt][1], 0, 0, 0);
            acc[mt][2] = __builtin_amdgcn_mfma_f32_16x16x32_f16(av, Bw[kk][2], acc[mt][2], 0, 0, 0);
            acc[mt][3] = __builtin_amdgcn_mfma_f32_16x16x32_f16(av, Bw[kk][3], acc[mt][3], 0, 0, 0);
        }

        // ---- 8-way K-split reduction (double-buffered) ----
#pragma unroll
        for (int mt = 0; mt < 2; ++mt)
#pragma unroll
            for (int nt = 0; nt < 4; ++nt)
                red[t & 1][mt][wave][nt][lane] = acc[mt][nt];
        __syncthreads();                          // barrier A (red ready)

        // ---- per-wave owner epilogue: sum, tanh, transpose, publish ----
        {
            float xr[4];
#pragma unroll
            for (int r = 0; r < 4; ++r) xr[r] = xs[t][mtO * 16 + quad * 4 + r];
            floatx4 s = red[t & 1][mtO][0][ntO][lane];
#pragma unroll
            for (int ww = 1; ww < 8; ++ww) s += red[t & 1][mtO][ww][ntO][lane];
#pragma unroll
            for (int r = 0; r < 4; ++r) {
                const float pre = s[r] + xr[r] * uvO + bvO;
                Tr[wave][quad * 4 + r][lq] = fast_tanh(pre);   // wave-private
            }
            // DS pipe is in-order within a wave: read back transposed
            const float4 fr = *(const float4*)&Tr[wave][lq][quad * 4];

            if (t < T_ - 1) {
                half4v hv;
                hv[0] = (half_t)fr.x; hv[1] = (half_t)fr.y;
                hv[2] = (half_t)fr.z; hv[3] = (half_t)fr.w;
                publish_u64(pout + pdst_o, __builtin_bit_cast(u64, hv));
                if (ROT) {
                    wave_signal(myflag_base + (size_t)t * (8 * 32 * 32));
                } else {
                    __syncthreads();  // barrier B (legacy path only)
                    if (tid == 0)
                        __hip_atomic_fetch_add(
                            myflag_base + (size_t)t * (8 * 32 * 32), 1u,
                            __ATOMIC_RELAXED, __HIP_MEMORY_SCOPE_AGENT);
                }
            } else {
                // final h_128 -> d_out fp32
                float* fd = hf32 + (size_t)(m0 + mtO * 16 + lq) * H_
                          + n0 + ntO * 16 + quad * 4;
                *(float4*)fd = make_float4(fr.x, fr.y, fr.z, fr.w);
                __syncthreads();      // all waves' Tr tiles complete
                // fused projection: partial out[32,10] = Tr-tiles @ V^T
                if (tid < 32 * C_) {
                    const int r = tid & 31, c = tid >> 5;    // c in [0,10)
                    float sacc = (C == 0) ? bp[c] : 0.0f;
                    const float* vr = V + (size_t)c * H_ + n0;
#pragma unroll 8
                    for (int n = 0; n < 64; ++n)
                        sacc += Tr[(n >> 4) * 2 + (r >> 4)][r & 15][n & 15] * vr[n];
                    atomicAdd(&outp[(size_t)(m0 + r) * C_ + c], sacc);
                }
            }
        }
    }
}

extern "C" void kernel_launch(void* const* d_in, const int* in_sizes, int n_in,
                              void* d_out, int out_size, void* d_ws, size_t ws_size,
                              hipStream_t stream) {
    const float* x  = (const float*)d_in[0];
    const float* U  = (const float*)d_in[1];
    const float* W  = (const float*)d_in[2];
    const float* V  = (const float*)d_in[3];
    const float* bh = (const float*)d_in[4];
    const float* bp = (const float*)d_in[5];

    float* out_h = (float*)d_out;                 // [B_*H_] fp32 h_last
    float* outp  = out_h + (size_t)B_ * H_;       // [B_*C_]

    unsigned* flags = (unsigned*)d_ws;                              // 4 MB
    half_t* hbase   = (half_t*)((char*)d_ws + (size_t)4 * 1024 * 1024);

    // rotation needs 4 MB flags + 127 x 1 MB slots = 131 MB
    const size_t need = (size_t)(4 + NSLOT) * 1024 * 1024;
    const int rot = ws_size >= need;

    hipMemsetAsync(flags, 0, FLAG_DWORDS * sizeof(unsigned), stream);
    hipMemsetAsync(outp, 0, (size_t)B_ * C_ * sizeof(float), stream);

    if (rot)
        rnn_persist<1><<<dim3(256), dim3(512), 0, stream>>>(
            x, U, W, bh, V, bp, hbase, out_h, outp, flags);
    else
        rnn_persist<0><<<dim3(256), dim3(512), 0, stream>>>(
            x, U, W, bh, V, bp, hbase, out_h, outp, flags);
}